// Round 1
// baseline (4040.621 us; speedup 1.0000x reference)
//
#include <hip/hip_runtime.h>
#include <hip/hip_bf16.h>

#define T_LEN 256
#define B_DIM 128
#define I_DIM 256
#define H_DIM 1024

typedef __attribute__((ext_vector_type(8))) short short8;
typedef __attribute__((ext_vector_type(4))) float f32x4;

// Per-cluster barrier counters (4 batch-quarter clusters, 128B apart).
// Monotonic within a call; re-zeroed by init_hT0 every call/replay.
__device__ unsigned g_bar[4][32];

// RNE float->bf16 (self-contained; inputs here are never NaN)
static __device__ __forceinline__ unsigned short f2bf(float f) {
  unsigned u = __float_as_uint(f);
  return (unsigned short)((u + 0x7fffu + ((u >> 16) & 1u)) >> 16);
}

// ---------------------------------------------------------------------------
// Phase 1: x_proj GEMM (fp32, unchanged).
// ---------------------------------------------------------------------------
__global__ __launch_bounds__(256) void xproj_gemm(
    const float* __restrict__ A, const float* __restrict__ W,
    const float* __restrict__ bias, float* __restrict__ C) {
  __shared__ float As[64][33];
  __shared__ float Ws[64][33];

  const int tid = threadIdx.x;
  const int m0 = blockIdx.y * 64;
  const int n0 = blockIdx.x * 64;
  const int ty = tid >> 4;
  const int tx = tid & 15;
  const int r   = tid >> 3;
  const int c4  = (tid & 7) << 2;

  float acc[4][4] = {};

  for (int kc = 0; kc < I_DIM; kc += 32) {
#pragma unroll
    for (int p = 0; p < 2; ++p) {
      const int rr = r + p * 32;
      const float4 a = *(const float4*)(A + (size_t)(m0 + rr) * I_DIM + kc + c4);
      As[rr][c4 + 0] = a.x; As[rr][c4 + 1] = a.y;
      As[rr][c4 + 2] = a.z; As[rr][c4 + 3] = a.w;
      const float4 w = *(const float4*)(W + (size_t)(n0 + rr) * I_DIM + kc + c4);
      Ws[rr][c4 + 0] = w.x; Ws[rr][c4 + 1] = w.y;
      Ws[rr][c4 + 2] = w.z; Ws[rr][c4 + 3] = w.w;
    }
    __syncthreads();
#pragma unroll
    for (int k = 0; k < 32; ++k) {
      float av[4], wv[4];
#pragma unroll
      for (int i = 0; i < 4; ++i) av[i] = As[ty * 4 + i][k];
#pragma unroll
      for (int j = 0; j < 4; ++j) wv[j] = Ws[tx * 4 + j][k];
#pragma unroll
      for (int i = 0; i < 4; ++i)
#pragma unroll
        for (int j = 0; j < 4; ++j)
          acc[i][j] = fmaf(av[i], wv[j], acc[i][j]);
    }
    __syncthreads();
  }

  const float4 bv = *(const float4*)(bias + n0 + tx * 4);
#pragma unroll
  for (int i = 0; i < 4; ++i) {
    float4 o;
    o.x = acc[i][0] + bv.x;
    o.y = acc[i][1] + bv.y;
    o.z = acc[i][2] + bv.z;
    o.w = acc[i][3] + bv.w;
    *(float4*)(C + (size_t)(m0 + ty * 4 + i) * H_DIM + n0 + tx * 4) = o;
  }
}

// ---------------------------------------------------------------------------
// One-time converts: W_hh -> bf16 [j][k]; hT0 -> bf16 [b][k] broadcast of h0.
// (ws is re-poisoned before every timed call, so these run every call.)
// init_hT0 also re-zeroes the persistent-kernel barrier counters.
// ---------------------------------------------------------------------------
__global__ __launch_bounds__(256) void cvt_w_bf16(
    const float* __restrict__ W, unsigned short* __restrict__ Wb) {
  const int i4 = blockIdx.x * 256 + threadIdx.x;     // one float4 per thread
  const float4 w = ((const float4*)W)[i4];
  ushort4 o;
  o.x = f2bf(w.x); o.y = f2bf(w.y); o.z = f2bf(w.z); o.w = f2bf(w.w);
  ((ushort4*)Wb)[i4] = o;
}

__global__ __launch_bounds__(256) void init_hT0(
    const float* __restrict__ h0, unsigned short* __restrict__ hT) {
  const int idx = blockIdx.x * 256 + threadIdx.x;    // [0, 131072)
  hT[idx] = f2bf(h0[idx & (H_DIM - 1)]);
  if (blockIdx.x == 0 && threadIdx.x < 128)
    ((unsigned*)g_bar)[threadIdx.x] = 0u;
}

// ---------------------------------------------------------------------------
// Phase 2: persistent cooperative kernel — whole time loop in ONE dispatch.
// Grid 256 = 64 j-tiles x 4 b-quarters (clusters). Block 256 thr = 4 waves:
// wave w -> m-tile (w&1) x k-half (w>>1). Same MFMA fragment mapping as the
// verified step kernel. W_hh fragments hoisted into registers (16 short8 =
// 64 VGPR; 1 block/CU so 512 VGPR/wave available). Per-step cross-block
// dependency is cluster-local (same bq), so sync = 64-block device-scope
// barrier: monotonic counter, one atomicAdd(agent,release)/block/step,
// tid0 spins on acquire load. __syncthreads drains vmcnt(0) before
// s_barrier, so all waves' stores are in L2 before the release flush.
// ---------------------------------------------------------------------------
__global__ __launch_bounds__(256, 1) void rnn_persist(
    unsigned short* __restrict__ hT,            // ping-pong base; parity0 = bf16(h0) bcast
    const unsigned short* __restrict__ Wb,      // [1024][1024] bf16
    const float* __restrict__ b_hh,
    const float* __restrict__ h0,
    float* __restrict__ out)                    // [T][B][H]: in x_proj, out h_t
{
  __shared__ float red[2][16][17];   // [m-tile][b_local][j_local], +1 pad

  const int tid  = threadIdx.x;
  const int wv   = tid >> 6;
  const int lane = tid & 63;
  const int ln   = lane & 15;        // A: b-row / B: j-row / D: j-col
  const int q    = lane >> 4;        // 0..3

  const int jt = blockIdx.x & 63;
  const int bq = blockIdx.x >> 6;
  const int j0 = jt * 16;
  const int mt = wv & 1;             // m-tile within the 32-b quarter
  const int kh = wv >> 1;            // k-half
  const int b0 = bq * 32 + mt * 16;

  // W fragments: resident in registers for the whole time loop.
  const short8* __restrict__ wb8 =
      (const short8*)(Wb + (size_t)(j0 + ln) * H_DIM + kh * 512 + q * 8);
  short8 wfrag[16];
#pragma unroll
  for (int kc = 0; kc < 16; ++kc) wfrag[kc] = wb8[kc * 4];

  const size_t HT = (size_t)B_DIM * H_DIM;     // 131072
  const size_t arow = (size_t)(b0 + ln) * H_DIM + kh * 512 + q * 8;
  const short8* __restrict__ ha0 = (const short8*)(hT + arow);
  const short8* __restrict__ ha1 = (const short8*)(hT + HT + arow);

  const int jg = j0 + ln;
  const float bj  = b_hh[jg];
  const float h0j = h0[jg];
  const size_t obase = (size_t)(b0 + q * 4) * H_DIM + jg;   // epilogue base (wv<2)

  unsigned* bar = &g_bar[bq][0];

  for (int t = 0; t < T_LEN; ++t) {
    float* __restrict__ xio_t = out + (size_t)t * HT;
    const float* __restrict__ hp_t = out + (size_t)(t - 1) * HT;  // not deref'd at t=0

    // Prefetch epilogue operands (independent of h_{t-1}) to overlap with MFMA.
    float xpv[4], hpv[4];
    if (wv < 2) {
#pragma unroll
      for (int r = 0; r < 4; ++r) {
        const size_t oidx = obase + (size_t)r * H_DIM;
        xpv[r] = xio_t[oidx];
        hpv[r] = (t == 0) ? h0j : hp_t[oidx];
      }
    }

    const short8* __restrict__ ha = (t & 1) ? ha1 : ha0;
    f32x4 acc0 = {0.f, 0.f, 0.f, 0.f};
    f32x4 acc1 = {0.f, 0.f, 0.f, 0.f};
#pragma unroll
    for (int kc = 0; kc < 16; kc += 2) {   // two independent MFMA chains
      acc0 = __builtin_amdgcn_mfma_f32_16x16x32_bf16(ha[kc * 4],       wfrag[kc],     acc0, 0, 0, 0);
      acc1 = __builtin_amdgcn_mfma_f32_16x16x32_bf16(ha[(kc + 1) * 4], wfrag[kc + 1], acc1, 0, 0, 0);
    }
    const f32x4 acc = acc0 + acc1;

    // D layout: j_col = lane&15, b_row = (lane>>4)*4 + reg.
    if (wv >= 2) {
#pragma unroll
      for (int r = 0; r < 4; ++r) red[mt][q * 4 + r][ln] = acc[r];
    }
    __syncthreads();
    if (wv < 2) {
      unsigned short* __restrict__ hnext = hT + (size_t)((t + 1) & 1) * HT;
#pragma unroll
      for (int r = 0; r < 4; ++r) {
        const float rec = acc[r] + red[mt][q * 4 + r][ln];
        float v = 0.9f * hpv[r] + 0.1f * (rec + bj + xpv[r]);
        v = v > 0.f ? v : 0.f;
        const size_t oidx = obase + (size_t)r * H_DIM;
        xio_t[oidx] = v;
        hnext[oidx] = f2bf(v);
      }
    }
    __syncthreads();   // drains all waves' stores (vmcnt(0)) before arrival
    if (tid == 0) {
      __hip_atomic_fetch_add(bar, 1u, __ATOMIC_RELEASE, __HIP_MEMORY_SCOPE_AGENT);
      const unsigned tgt = (unsigned)(t + 1) * 64u;
      while (__hip_atomic_load(bar, __ATOMIC_ACQUIRE, __HIP_MEMORY_SCOPE_AGENT) < tgt)
        __builtin_amdgcn_s_sleep(2);
    }
    __syncthreads();
  }
}

// ---------------------------------------------------------------------------
extern "C" void kernel_launch(void* const* d_in, const int* in_sizes, int n_in,
                              void* d_out, int out_size, void* d_ws, size_t ws_size,
                              hipStream_t stream) {
  const float* input = (const float*)d_in[0];
  const float* W_in  = (const float*)d_in[1];
  const float* b_in  = (const float*)d_in[2];
  const float* W_hh  = (const float*)d_in[3];
  const float* b_hh  = (const float*)d_in[4];
  const float* h0    = (const float*)d_in[5];
  float* out = (float*)d_out;

  // ws layout: [0, 2MB) Wb bf16 [1024][1024]; then hT ping-pong 2 x 256 KB.
  unsigned short* Wb = (unsigned short*)d_ws;
  unsigned short* hT = Wb + (1 << 20);

  cvt_w_bf16<<<(H_DIM * H_DIM / 4) / 256, 256, 0, stream>>>(W_hh, Wb);
  init_hT0<<<(B_DIM * H_DIM) / 256, 256, 0, stream>>>(h0, hT);

  dim3 g1(H_DIM / 64, (T_LEN * B_DIM) / 64);
  xproj_gemm<<<g1, 256, 0, stream>>>(input, W_in, b_in, out);

  {
    unsigned short* hT_ = hT;
    const unsigned short* Wb_ = Wb;
    const float* bhh_ = b_hh;
    const float* h0_ = h0;
    float* out_ = out;
    void* pargs[5] = {(void*)&hT_, (void*)&Wb_, (void*)&bhh_, (void*)&h0_, (void*)&out_};
    hipLaunchCooperativeKernel((const void*)rnn_persist, dim3(256), dim3(256),
                               pargs, 0, stream);
  }
}

// Round 3
// 2925.990 us; speedup vs baseline: 1.3809x; 1.3809x over previous
//
#include <hip/hip_runtime.h>
#include <hip/hip_bf16.h>

#define T_LEN 256
#define B_DIM 128
#define I_DIM 256
#define H_DIM 1024

typedef __attribute__((ext_vector_type(8))) short short8;
typedef __attribute__((ext_vector_type(4))) float f32x4;

// Per-cluster barrier counters (4 batch-quarter clusters, 128B apart).
// Monotonic within a call; re-zeroed by init_hT0 every call/replay.
__device__ unsigned g_bar[4][32];

// RNE float->bf16 (self-contained; inputs here are never NaN)
static __device__ __forceinline__ unsigned short f2bf(float f) {
  unsigned u = __float_as_uint(f);
  return (unsigned short)((u + 0x7fffu + ((u >> 16) & 1u)) >> 16);
}

// ---------------------------------------------------------------------------
// Phase 1: x_proj GEMM (fp32, unchanged).
// ---------------------------------------------------------------------------
__global__ __launch_bounds__(256) void xproj_gemm(
    const float* __restrict__ A, const float* __restrict__ W,
    const float* __restrict__ bias, float* __restrict__ C) {
  __shared__ float As[64][33];
  __shared__ float Ws[64][33];

  const int tid = threadIdx.x;
  const int m0 = blockIdx.y * 64;
  const int n0 = blockIdx.x * 64;
  const int ty = tid >> 4;
  const int tx = tid & 15;
  const int r   = tid >> 3;
  const int c4  = (tid & 7) << 2;

  float acc[4][4] = {};

  for (int kc = 0; kc < I_DIM; kc += 32) {
#pragma unroll
    for (int p = 0; p < 2; ++p) {
      const int rr = r + p * 32;
      const float4 a = *(const float4*)(A + (size_t)(m0 + rr) * I_DIM + kc + c4);
      As[rr][c4 + 0] = a.x; As[rr][c4 + 1] = a.y;
      As[rr][c4 + 2] = a.z; As[rr][c4 + 3] = a.w;
      const float4 w = *(const float4*)(W + (size_t)(n0 + rr) * I_DIM + kc + c4);
      Ws[rr][c4 + 0] = w.x; Ws[rr][c4 + 1] = w.y;
      Ws[rr][c4 + 2] = w.z; Ws[rr][c4 + 3] = w.w;
    }
    __syncthreads();
#pragma unroll
    for (int k = 0; k < 32; ++k) {
      float av[4], wv[4];
#pragma unroll
      for (int i = 0; i < 4; ++i) av[i] = As[ty * 4 + i][k];
#pragma unroll
      for (int j = 0; j < 4; ++j) wv[j] = Ws[tx * 4 + j][k];
#pragma unroll
      for (int i = 0; i < 4; ++i)
#pragma unroll
        for (int j = 0; j < 4; ++j)
          acc[i][j] = fmaf(av[i], wv[j], acc[i][j]);
    }
    __syncthreads();
  }

  const float4 bv = *(const float4*)(bias + n0 + tx * 4);
#pragma unroll
  for (int i = 0; i < 4; ++i) {
    float4 o;
    o.x = acc[i][0] + bv.x;
    o.y = acc[i][1] + bv.y;
    o.z = acc[i][2] + bv.z;
    o.w = acc[i][3] + bv.w;
    *(float4*)(C + (size_t)(m0 + ty * 4 + i) * H_DIM + n0 + tx * 4) = o;
  }
}

// ---------------------------------------------------------------------------
// One-time converts: W_hh -> bf16 [j][k]; hT0 -> bf16 [b][k] broadcast of h0.
// init_hT0 also re-zeroes the persistent-kernel barrier counters.
// ---------------------------------------------------------------------------
__global__ __launch_bounds__(256) void cvt_w_bf16(
    const float* __restrict__ W, unsigned short* __restrict__ Wb) {
  const int i4 = blockIdx.x * 256 + threadIdx.x;     // one float4 per thread
  const float4 w = ((const float4*)W)[i4];
  ushort4 o;
  o.x = f2bf(w.x); o.y = f2bf(w.y); o.z = f2bf(w.z); o.w = f2bf(w.w);
  ((ushort4*)Wb)[i4] = o;
}

__global__ __launch_bounds__(256) void init_hT0(
    const float* __restrict__ h0, unsigned short* __restrict__ hT) {
  const int idx = blockIdx.x * 256 + threadIdx.x;    // [0, 131072)
  hT[idx] = f2bf(h0[idx & (H_DIM - 1)]);
  if (blockIdx.x == 0 && threadIdx.x < 128)
    ((unsigned*)g_bar)[threadIdx.x] = 0u;
}

// ---------------------------------------------------------------------------
// Phase 2: persistent cooperative kernel — whole time loop in ONE dispatch.
// Grid 256 = 64 j-tiles x 4 b-quarter clusters. Block 256 thr = 4 waves.
//
// Sync protocol (round-2 deadlock fix):
//  - hnext / xio stores: RELAXED agent atomic stores -> write-through (sc1),
//    no dirty L2 lines for the recurrent state.
//  - Arrival: RELEASE agent fetch_add (round-1-proven). Emits one buffer_wbl2
//    per block per step — cheap, L2 is nearly clean thanks to write-through.
//  - Spin: inline-asm global_load sc0 sc1 — bypasses L1 AND the local XCD L2,
//    reads the coherence point every poll. Guaranteed progress (round 2's
//    relaxed atomic-load spin could livelock on a stale local-L2 line; round
//    1's acquire spin made progress only via per-poll buffer_inv = 527 MB of
//    HBM refetch). No cache maintenance in the loop.
//  - Exactly ONE acquire fence (buffer_inv) per step, tid0, after the spin:
//    next step's plain short8 h-loads can't hit stale L1/L2 lines. Other
//    waves are held at the following s_barrier until after the inv.
//  - W fragments pinned in VGPRs (asm keep-alive) so the per-step inv never
//    forces a W refetch. h_prev fp32 carried in registers (same thread
//    produced it last step) -> no 512 KB/step cold HBM read.
// ---------------------------------------------------------------------------
__global__ __launch_bounds__(256, 1) void rnn_persist(
    unsigned short* __restrict__ hT,            // ping-pong; parity0 = bf16(h0)
    const unsigned short* __restrict__ Wb,      // [1024][1024] bf16
    const float* __restrict__ b_hh,
    const float* __restrict__ h0,
    float* __restrict__ out)                    // [T][B][H]: in x_proj, out h_t
{
  __shared__ float red[2][16][17];   // [m-tile][b_local][j_local], +1 pad

  const int tid  = threadIdx.x;
  const int wv   = tid >> 6;
  const int lane = tid & 63;
  const int ln   = lane & 15;        // A: b-row / B: j-row / D: j-col
  const int q    = lane >> 4;        // 0..3

  const int jt = blockIdx.x & 63;
  const int bq = blockIdx.x >> 6;
  const int j0 = jt * 16;
  const int mt = wv & 1;             // m-tile within the 32-b quarter
  const int kh = wv >> 1;            // k-half
  const int b0 = bq * 32 + mt * 16;

  // W fragments: load once, pin in VGPRs for the whole time loop.
  const short8* __restrict__ wb8 =
      (const short8*)(Wb + (size_t)(j0 + ln) * H_DIM + kh * 512 + q * 8);
  short8 wfrag[16];
#pragma unroll
  for (int kc = 0; kc < 16; ++kc) wfrag[kc] = wb8[kc * 4];
#pragma unroll
  for (int kc = 0; kc < 16; ++kc) asm volatile("" : "+v"(wfrag[kc]));

  const size_t HT = (size_t)B_DIM * H_DIM;     // 131072
  const size_t arow = (size_t)(b0 + ln) * H_DIM + kh * 512 + q * 8;
  const short8* __restrict__ ha0 = (const short8*)(hT + arow);
  const short8* __restrict__ ha1 = (const short8*)(hT + HT + arow);

  const int jg = j0 + ln;
  const float bj  = b_hh[jg];
  const size_t obase = (size_t)(b0 + q * 4) * H_DIM + jg;   // epilogue base (wv<2)

  // fp32 h_prev carried in registers (this thread wrote the same (b,j) slots
  // last step). t=0 uses h0.
  float hcur[4];
  {
    const float h0j = h0[jg];
#pragma unroll
    for (int r = 0; r < 4; ++r) hcur[r] = h0j;
  }

  unsigned* bar = &g_bar[bq][0];

  for (int t = 0; t < T_LEN; ++t) {
    float* __restrict__ xio_t = out + (size_t)t * HT;

    // Prefetch x_proj[t] (independent of h_{t-1}) to overlap with MFMA.
    float xpv[4];
    if (wv < 2) {
#pragma unroll
      for (int r = 0; r < 4; ++r) xpv[r] = xio_t[obase + (size_t)r * H_DIM];
    }

    const short8* __restrict__ ha = (t & 1) ? ha1 : ha0;
    f32x4 acc0 = {0.f, 0.f, 0.f, 0.f};
    f32x4 acc1 = {0.f, 0.f, 0.f, 0.f};
#pragma unroll
    for (int kc = 0; kc < 16; kc += 2) {   // two independent MFMA chains
      acc0 = __builtin_amdgcn_mfma_f32_16x16x32_bf16(ha[kc * 4],       wfrag[kc],     acc0, 0, 0, 0);
      acc1 = __builtin_amdgcn_mfma_f32_16x16x32_bf16(ha[(kc + 1) * 4], wfrag[kc + 1], acc1, 0, 0, 0);
    }
    const f32x4 acc = acc0 + acc1;

    // D layout: j_col = lane&15, b_row = (lane>>4)*4 + reg.
    if (wv >= 2) {
#pragma unroll
      for (int r = 0; r < 4; ++r) red[mt][q * 4 + r][ln] = acc[r];
    }
    __syncthreads();
    if (wv < 2) {
      unsigned short* __restrict__ hnext = hT + (size_t)((t + 1) & 1) * HT;
#pragma unroll
      for (int r = 0; r < 4; ++r) {
        const float rec = acc[r] + red[mt][q * 4 + r][ln];
        float v = 0.9f * hcur[r] + 0.1f * (rec + bj + xpv[r]);
        v = v > 0.f ? v : 0.f;
        hcur[r] = v;
        const size_t oidx = obase + (size_t)r * H_DIM;
        // Write-through (relaxed agent) stores -> no dirty L2 for h state.
        __hip_atomic_store(&xio_t[oidx], v, __ATOMIC_RELAXED,
                           __HIP_MEMORY_SCOPE_AGENT);
        __hip_atomic_store(&hnext[oidx], f2bf(v), __ATOMIC_RELAXED,
                           __HIP_MEMORY_SCOPE_AGENT);
      }
    }
    __syncthreads();   // all waves' stores drained (vmcnt 0) before arrival
    if (tid == 0) {
      // Release arrival: wbl2 + device-coherent add (round-1-proven path).
      __hip_atomic_fetch_add(bar, 1u, __ATOMIC_RELEASE, __HIP_MEMORY_SCOPE_AGENT);
      const unsigned tgt = (unsigned)(t + 1) * 64u;
      // Spin with explicit L1+L2-bypass loads: coherent AND maintenance-free.
      unsigned cur;
      for (;;) {
        asm volatile("global_load_dword %0, %1, off sc0 sc1\n\t"
                     "s_waitcnt vmcnt(0)"
                     : "=v"(cur) : "v"(bar) : "memory");
        if (cur >= tgt) break;
        __builtin_amdgcn_s_sleep(4);
      }
      // One L1+L2 invalidate per step so next step's plain h-loads are fresh.
      __builtin_amdgcn_fence(__ATOMIC_ACQUIRE, "agent");
    }
    __syncthreads();
  }
}

// ---------------------------------------------------------------------------
extern "C" void kernel_launch(void* const* d_in, const int* in_sizes, int n_in,
                              void* d_out, int out_size, void* d_ws, size_t ws_size,
                              hipStream_t stream) {
  const float* input = (const float*)d_in[0];
  const float* W_in  = (const float*)d_in[1];
  const float* b_in  = (const float*)d_in[2];
  const float* W_hh  = (const float*)d_in[3];
  const float* b_hh  = (const float*)d_in[4];
  const float* h0    = (const float*)d_in[5];
  float* out = (float*)d_out;

  // ws layout: [0, 2MB) Wb bf16 [1024][1024]; then hT ping-pong 2 x 256 KB.
  unsigned short* Wb = (unsigned short*)d_ws;
  unsigned short* hT = Wb + (1 << 20);

  cvt_w_bf16<<<(H_DIM * H_DIM / 4) / 256, 256, 0, stream>>>(W_hh, Wb);
  init_hT0<<<(B_DIM * H_DIM) / 256, 256, 0, stream>>>(h0, hT);

  dim3 g1(H_DIM / 64, (T_LEN * B_DIM) / 64);
  xproj_gemm<<<g1, 256, 0, stream>>>(input, W_in, b_in, out);

  {
    unsigned short* hT_ = hT;
    const unsigned short* Wb_ = Wb;
    const float* bhh_ = b_hh;
    const float* h0_ = h0;
    float* out_ = out;
    void* pargs[5] = {(void*)&hT_, (void*)&Wb_, (void*)&bhh_, (void*)&h0_, (void*)&out_};
    hipLaunchCooperativeKernel((const void*)rnn_persist, dim3(256), dim3(256),
                               pargs, 0, stream);
  }
}